// Round 4
// baseline (310.361 us; speedup 1.0000x reference)
//
#include <hip/hip_runtime.h>

// BSQ forward: x (65536x512 f32) -> z (x16) -> sign bits -> decode (x512).
// Normalize is sign-invariant -> skipped; STE forward output == sign(z).
//
// NUMERICS: must match numpy baseline-SSE sign decisions bitwise:
//   per 16-chunk, 4 partials p[k], reversed subvector chain
//   (p_k = x[16i+k]*w + (x[16i+4+k]*w + (x[16i+8+k]*w + (x[16i+12+k]*w + p_k)))),
//   SSE3 hadd tree (p0+p1)+(p2+p3), then +b_enc as a separate add.
// File-scope `fp contract(off)` blocks FMA fusion (decode uses explicit fma,
// unaffected, matching the previously verified absmax=0.0078).
//
// vs 113-115us versions: encode restructured LANE=TOKEN. The old (tsub,c)
// layout read every x fragment 16x (broadcast) -> ~4096 ds_read_b128/block,
// ~60% of kernel cycles on the LDS return path (hidden from all counters;
// explains R2's null result after conflicts hit 0). Now:
//  - wave = 64 tokens x one k-half; k-half is WAVE-uniform (wv&1) so the
//    numpy partial-pair split costs one LDS exchange at the end, in exact
//    hadd order.
//  - x staged per wave-pair (64tok x 64dims, double-buffered, XOR-swizzled
//    16-slot rows); reads are per-lane-unique ds_read_b64 -> 16x less LDS.
//  - W repacked by a tiny pre-pass kernel into k-half-major layout in d_ws;
//    main kernel reads it at scalar (readfirstlane'd) addresses -> SMEM pipe.
// R4 fix: bsq_wprep bit positions (c at bit 8, kh at bit 12, 8192 floats)
// now match the main kernel's read layout kh*4096 + c*256 + s*32 + m*2 + e.

#pragma clang fp contract(off)

typedef float v2f __attribute__((ext_vector_type(2)));

constexpr int DIM     = 512;
constexpr int NC      = 16;
constexpr int TPB_TOK = 128;    // tokens per block (2 groups x 64)
constexpr int NTOK    = 65536;

__device__ __forceinline__ float add_rn(float a, float b) { return __fadd_rn(a, b); }
__device__ __forceinline__ v2f mk2(float a, float b) { v2f r; r.x = a; r.y = b; return r; }

// Wp[kh*4096 + c*256 + s*32 + m*2 + e]
//   = Wenc[c][s*64 + (m>>2)*16 + (m&3)*4 + 2*kh + e]
// (chunk i = 4s + (m>>2), subvector j = m&3, SSE lane k = 2*kh + e)
__global__ void bsq_wprep(const float* __restrict__ Wenc, float* __restrict__ Wp)
{
    for (int idx = threadIdx.x; idx < 8192; idx += 256) {
        int e = idx & 1, m = (idx >> 1) & 15, s = (idx >> 5) & 7,
            c = (idx >> 8) & 15, kh = idx >> 12;
        Wp[idx] = Wenc[c * 512 + s * 64 + (m >> 2) * 16 + (m & 3) * 4 + 2 * kh + e];
    }
}

__global__ __launch_bounds__(256, 2) void bsq_main(
    const float* __restrict__ x,
    const float* __restrict__ Wp,     // repacked W_enc (32 KB, in d_ws)
    const float* __restrict__ benc,
    const float* __restrict__ Wdec,   // (512, 16)
    const float* __restrict__ bdec,
    float* __restrict__ out)
{
    // x slab: [buf][group][token*16 + swizzled f4 slot]; row = 256B = 16 slots,
    // slot = j ^ (t&15). 64 KB. s_t: kh=1 waves' (p2+p3) per [g][c][token].
    __shared__ float4   s_x[2][2][1024];     // 64 KB
    __shared__ float    s_t[2][16][64];      // 8 KB
    __shared__ unsigned s_codes[128];

    const int tid  = threadIdx.x;
    const int lane = tid & 63;
    const int wv   = tid >> 6;
    const int kh   = wv & 1;                 // k-half: 0 -> (p0,p1), 1 -> (p2,p3)
    const int g    = wv >> 1;                // token group (64 tokens each)
    const int kh_u = __builtin_amdgcn_readfirstlane(kh);   // scalar for W addr
    const size_t tokB = (size_t)blockIdx.x * TPB_TOK;

    const float4* xg4 = (const float4*)(x + (tokB + (size_t)g * 64) * DIM);
    const int tl = 4 * kh + (lane >> 4);     // staging row-within-op (pair covers 8 rows)
    const int jj = lane & 15;
    const int lmask16 = (lane & 15) * 16;    // read-swizzle XOR mask (bytes)

    float4 pf[8];
    // coalesced: per op, 8 rows x 256B contiguous across the wave pair
#define GLOAD(S) { _Pragma("unroll") for (int op = 0; op < 8; ++op) { \
        int t = op * 8 + tl; pf[op] = xg4[t * 128 + (S) * 16 + jj]; } }
#define SWRITE(BUF) { _Pragma("unroll") for (int op = 0; op < 8; ++op) { \
        int t = op * 8 + tl; s_x[BUF][g][t * 16 + (jj ^ (t & 15))] = pf[op]; } }

    v2f acc[16];                             // acc[c] = (p_{2kh}, p_{2kh+1})
#pragma unroll
    for (int c = 0; c < 16; ++c) acc[c] = mk2(0.f, 0.f);

    // prologue: stage 0 into buf0, stage 1 in flight
    GLOAD(0); SWRITE(0); GLOAD(1);
    __syncthreads();

    for (int sp = 0; sp < 8; sp += 2) {
#pragma unroll
        for (int half = 0; half < 2; ++half) {
            const int s = sp + half;                     // uniform; buf = s&1 = half
            // lane's token row: pairs (4m+2kh, 4m+2kh+1) of dims [64s, 64s+64)
            v2f xr[16];
            const char* rb = (const char*)&s_x[half][g][lane * 16] + kh_u * 8;
#pragma unroll
            for (int m = 0; m < 16; ++m)
                xr[m] = *(const v2f*)(rb + ((m * 16) ^ lmask16));
            if (s < 7) { SWRITE(half ^ 1); }             // park stage s+1
            if (s < 6) { GLOAD(s + 2); }                 // issue stage s+2
            __syncthreads();

            // ---- numpy chain, chunks i = 4s+ci, this wave's k-pair ----
#pragma unroll
            for (int c = 0; c < 16; ++c) {
                const v2f* wrow = (const v2f*)(Wp + (((kh_u * 16 + c) * 8 + s) << 5));
                v2f w[16];
#pragma unroll
                for (int m = 0; m < 16; ++m) w[m] = wrow[m];  // scalar loads
                v2f p = acc[c], t;
#pragma unroll
                for (int ci = 0; ci < 4; ++ci) {
                    t = xr[ci * 4 + 3] * w[ci * 4 + 3] + p;   // unfused pk mul+add
                    t = xr[ci * 4 + 2] * w[ci * 4 + 2] + t;
                    t = xr[ci * 4 + 1] * w[ci * 4 + 1] + t;
                    p = xr[ci * 4 + 0] * w[ci * 4 + 0] + t;
                }
                acc[c] = p;
            }
        }
    }

    // ---- combine halves in exact hadd order: (p0+p1) + (p2+p3), then +b ----
    if (kh == 1) {
#pragma unroll
        for (int c = 0; c < 16; ++c)
            s_t[g][c][lane] = add_rn(acc[c].x, acc[c].y);     // p2+p3
    }
    __syncthreads();
    if (kh == 0) {
        float bencv[16];
        {
            const float4* b4 = (const float4*)benc;
#pragma unroll
            for (int p = 0; p < 4; ++p) {
                float4 v = b4[p];
                bencv[p * 4 + 0] = v.x; bencv[p * 4 + 1] = v.y;
                bencv[p * 4 + 2] = v.z; bencv[p * 4 + 3] = v.w;
            }
        }
        unsigned code = 0;
#pragma unroll
        for (int c = 0; c < 16; ++c) {
            float zs = add_rn(add_rn(acc[c].x, acc[c].y), s_t[g][c][lane]);
            float z  = add_rn(zs, bencv[c]);
            code |= (z >= 0.0f ? 1u : 0u) << c;
        }
        s_codes[g * 64 + lane] = code;
    }
    __syncthreads();

    // ---- decode: thread owns output columns 2*tid, 2*tid+1 ----
    v2f w01[NC];
    {
        const float4* wrow = (const float4*)(Wdec + tid * 32);
        float4 ra[4], rb4[4];
#pragma unroll
        for (int p = 0; p < 4; ++p) ra[p] = wrow[p];
#pragma unroll
        for (int p = 0; p < 4; ++p) rb4[p] = wrow[4 + p];
#pragma unroll
        for (int p = 0; p < 4; ++p) {
            w01[p * 4 + 0] = mk2(ra[p].x, rb4[p].x);
            w01[p * 4 + 1] = mk2(ra[p].y, rb4[p].y);
            w01[p * 4 + 2] = mk2(ra[p].z, rb4[p].z);
            w01[p * 4 + 3] = mk2(ra[p].w, rb4[p].w);
        }
    }
    const float2 bdv = *(const float2*)(bdec + 2 * tid);
    const v2f ob = mk2(bdv.x, bdv.y);
    float* op = out + tokB * DIM + 2 * tid;

    int cv0 = (int)s_codes[lane];
    int cv1 = (int)s_codes[64 + lane];
#pragma unroll 4
    for (int t2 = 0; t2 < 64; ++t2) {
        unsigned code = (unsigned)__builtin_amdgcn_readlane(cv0, t2);  // uniform
        v2f o = ob;
#pragma unroll
        for (int cc = 0; cc < NC; ++cc) {
            float sgn = ((code >> cc) & 1u) ? 1.0f : -1.0f;
            o = __builtin_elementwise_fma(w01[cc], mk2(sgn, sgn), o);
        }
        *(float2*)(op + (size_t)t2 * DIM) = make_float2(o.x, o.y);
    }
#pragma unroll 4
    for (int t2 = 64; t2 < 128; ++t2) {
        unsigned code = (unsigned)__builtin_amdgcn_readlane(cv1, t2 - 64);
        v2f o = ob;
#pragma unroll
        for (int cc = 0; cc < NC; ++cc) {
            float sgn = ((code >> cc) & 1u) ? 1.0f : -1.0f;
            o = __builtin_elementwise_fma(w01[cc], mk2(sgn, sgn), o);
        }
        *(float2*)(op + (size_t)t2 * DIM) = make_float2(o.x, o.y);
    }
#undef GLOAD
#undef SWRITE
}

extern "C" void kernel_launch(void* const* d_in, const int* in_sizes, int n_in,
                              void* d_out, int out_size, void* d_ws, size_t ws_size,
                              hipStream_t stream) {
    const float* x    = (const float*)d_in[0];
    const float* Wenc = (const float*)d_in[1];
    const float* benc = (const float*)d_in[2];
    const float* Wdec = (const float*)d_in[3];
    const float* bdec = (const float*)d_in[4];
    float* out = (float*)d_out;
    float* Wp  = (float*)d_ws;    // 32 KB repack

    bsq_wprep<<<dim3(1), dim3(256), 0, stream>>>(Wenc, Wp);
    bsq_main<<<dim3(NTOK / TPB_TOK), dim3(256), 0, stream>>>(x, Wp, benc, Wdec, bdec, out);
}